// Round 1
// baseline (368.216 us; speedup 1.0000x reference)
//
#include <hip/hip_runtime.h>
#include <math.h>

#define V 128
#define M 256
#define CAT 64
#define B 256
#define LAYERS 4
#define N 32768
#define K 4
#define AR 2
#define E (N * K)
#define NUM_INPUT (V * M)
#define BASE (1 + NUM_INPUT)
#define TOTAL_ROWS (BASE + LAYERS * N)   // 163841

// ---------------- Kernel A: input layer ----------------
// One block per input node n. Compute log-softmax of its 64 logits, then
// for each batch b write logp[cat(n,b)] into node row (1+n).
__global__ __launch_bounds__(256) void input_layer_kernel(
    const int* __restrict__ inputs,          // [B, V] int32
    const float* __restrict__ input_logits,  // [NUM_INPUT, CAT]
    float* __restrict__ buf)                 // [TOTAL_ROWS, B]
{
    __shared__ float lg[CAT];
    __shared__ float logZ_s;
    const int n = blockIdx.x;
    const int t = threadIdx.x;

    if (t < CAT) lg[t] = input_logits[(size_t)n * CAT + t];
    __syncthreads();

    if (t < 64) {  // wave 0 reduces the 64 logits
        float x = lg[t];
        float m = x;
        #pragma unroll
        for (int off = 32; off >= 1; off >>= 1) m = fmaxf(m, __shfl_xor(m, off));
        float s = __expf(x - m);
        #pragma unroll
        for (int off = 32; off >= 1; off >>= 1) s += __shfl_xor(s, off);
        if (t == 0) logZ_s = m + __logf(s);
    }
    __syncthreads();

    const float logZ = logZ_s;
    const int vid = n >> 8;                      // n / M
    const int cat = inputs[t * V + vid];         // inputs[b, vid], b = t
    buf[(size_t)(1 + n) * B + t] = lg[cat] - logZ;
    if (n == 0) buf[t] = 0.0f;                   // dummy node row 0
}

// ---------------- Kernel B: fused prod+sum layer ----------------
// One block per sum node i. Gather 8 child rows, pairwise add (product in
// log space), add grouped-softmax log weights, logsumexp over K=4.
__global__ __launch_bounds__(256) void layer_kernel(
    const int* __restrict__ child,   // [E, AR] for this layer (e = i*K + k)
    const float* __restrict__ slog,  // [N, K] for this layer
    float* __restrict__ buf,         // [TOTAL_ROWS, B]
    int out_row0)
{
    __shared__ int ch[K * AR];
    __shared__ float lw[K];
    const int i = blockIdx.x;
    const int t = threadIdx.x;

    if (t < K * AR) ch[t] = child[(size_t)i * (K * AR) + t];
    if (t == 8) {
        const float x0 = slog[(size_t)i * K + 0];
        const float x1 = slog[(size_t)i * K + 1];
        const float x2 = slog[(size_t)i * K + 2];
        const float x3 = slog[(size_t)i * K + 3];
        const float m = fmaxf(fmaxf(x0, x1), fmaxf(x2, x3));
        const float lz = m + __logf(__expf(x0 - m) + __expf(x1 - m) +
                                    __expf(x2 - m) + __expf(x3 - m));
        lw[0] = x0 - lz; lw[1] = x1 - lz; lw[2] = x2 - lz; lw[3] = x3 - lz;
    }
    __syncthreads();

    const float v0 = buf[(size_t)ch[0] * B + t] + buf[(size_t)ch[1] * B + t] + lw[0];
    const float v1 = buf[(size_t)ch[2] * B + t] + buf[(size_t)ch[3] * B + t] + lw[1];
    const float v2 = buf[(size_t)ch[4] * B + t] + buf[(size_t)ch[5] * B + t] + lw[2];
    const float v3 = buf[(size_t)ch[6] * B + t] + buf[(size_t)ch[7] * B + t] + lw[3];

    const float m = fmaxf(fmaxf(v0, v1), fmaxf(v2, v3));
    const float out = m + __logf(__expf(v0 - m) + __expf(v1 - m) +
                                 __expf(v2 - m) + __expf(v3 - m));
    buf[(size_t)(out_row0 + i) * B + t] = out;
}

// ---------------- Kernel C: root partials ----------------
// Block p accumulates an online logsumexp over rows n = p, p+P, ... of the
// last layer (+ raw root logits; normalizer subtracted at combine time).
__global__ __launch_bounds__(256) void root_partial_kernel(
    const float* __restrict__ buf,
    const float* __restrict__ rlog,  // [N]
    float* __restrict__ pm, float* __restrict__ ps)
{
    const int p = blockIdx.x;
    const int t = threadIdx.x;
    const float* last = buf + (size_t)(BASE + (LAYERS - 1) * N) * B;

    float m = -INFINITY, s = 0.0f;
    for (int n = p; n < N; n += gridDim.x) {
        const float v = last[(size_t)n * B + t] + rlog[n];
        if (v <= m) {
            s += __expf(v - m);
        } else {
            s = s * __expf(m - v) + 1.0f;
            m = v;
        }
    }
    pm[p * B + t] = m;
    ps[p * B + t] = s;
}

// ---------------- Kernel D: combine + root normalizer ----------------
__global__ __launch_bounds__(256) void root_combine_kernel(
    const float* __restrict__ rlog,
    const float* __restrict__ pm, const float* __restrict__ ps,
    float* __restrict__ out, int P)
{
    __shared__ float red[256];
    const int t = threadIdx.x;

    // logZ of root logits (block-wide two-pass reduce)
    float lm = -INFINITY;
    for (int n = t; n < N; n += 256) lm = fmaxf(lm, rlog[n]);
    red[t] = lm;
    __syncthreads();
    for (int off = 128; off >= 1; off >>= 1) {
        if (t < off) red[t] = fmaxf(red[t], red[t + off]);
        __syncthreads();
    }
    const float gm = red[0];
    __syncthreads();
    float ls = 0.0f;
    for (int n = t; n < N; n += 256) ls += __expf(rlog[n] - gm);
    red[t] = ls;
    __syncthreads();
    for (int off = 128; off >= 1; off >>= 1) {
        if (t < off) red[t] += red[t + off];
        __syncthreads();
    }
    const float logZ = gm + __logf(red[0]);

    // combine partials for batch column t
    float m = -INFINITY, s = 0.0f;
    for (int p = 0; p < P; ++p) {
        const float pmv = pm[p * B + t];
        const float psv = ps[p * B + t];
        if (pmv <= m) {
            s += psv * __expf(pmv - m);
        } else {
            s = s * __expf(m - pmv) + psv;
            m = pmv;
        }
    }
    out[t] = m + __logf(s) - logZ;
}

extern "C" void kernel_launch(void* const* d_in, const int* in_sizes, int n_in,
                              void* d_out, int out_size, void* d_ws, size_t ws_size,
                              hipStream_t stream) {
    const int*   inputs       = (const int*)d_in[0];    // [B, V]
    const float* input_logits = (const float*)d_in[1];  // [NUM_INPUT, CAT]
    const float* sum_logits   = (const float*)d_in[2];  // [LAYERS, N, K]
    const float* root_logits  = (const float*)d_in[3];  // [N]
    const int*   child        = (const int*)d_in[4];    // [LAYERS, E, AR]
    float* out = (float*)d_out;                          // [B, 1]

    float* buf = (float*)d_ws;                           // [TOTAL_ROWS, B]
    const size_t buf_elems = (size_t)TOTAL_ROWS * B;
    float* pm = buf + buf_elems;                         // [P, B]
    float* ps = pm + (size_t)256 * B;                    // [P, B]

    input_layer_kernel<<<NUM_INPUT, 256, 0, stream>>>(inputs, input_logits, buf);

    for (int l = 0; l < LAYERS; ++l) {
        layer_kernel<<<N, 256, 0, stream>>>(
            child + (size_t)l * E * AR,
            sum_logits + (size_t)l * N * K,
            buf,
            BASE + l * N);
    }

    const int P = 256;
    root_partial_kernel<<<P, 256, 0, stream>>>(buf, root_logits, pm, ps);
    root_combine_kernel<<<1, 256, 0, stream>>>(root_logits, pm, ps, out, P);
}

// Round 2
// 238.565 us; speedup vs baseline: 1.5435x; 1.5435x over previous
//
#include <hip/hip_runtime.h>
#include <math.h>

#define V 128
#define M 256
#define CAT 64
#define B 256
#define LAYERS 4
#define N 32768
#define K 4
#define AR 2
#define E (N * K)
#define NUM_INPUT (V * M)
#define BASE (1 + NUM_INPUT)
#define TOTAL_ROWS (BASE + LAYERS * N)   // 163841
#define PPART 256

// ---------------- Kernel A: input layer ----------------
__global__ __launch_bounds__(256) void input_layer_kernel(
    const int* __restrict__ inputs,          // [B, V] int32
    const float* __restrict__ input_logits,  // [NUM_INPUT, CAT]
    float* __restrict__ buf)                 // [TOTAL_ROWS, B]
{
    __shared__ float lg[CAT];
    __shared__ float logZ_s;
    const int n = blockIdx.x;
    const int t = threadIdx.x;

    if (t < CAT) lg[t] = input_logits[(size_t)n * CAT + t];
    __syncthreads();

    if (t < 64) {  // wave 0 reduces the 64 logits
        float x = lg[t];
        float m = x;
        #pragma unroll
        for (int off = 32; off >= 1; off >>= 1) m = fmaxf(m, __shfl_xor(m, off));
        float s = __expf(x - m);
        #pragma unroll
        for (int off = 32; off >= 1; off >>= 1) s += __shfl_xor(s, off);
        if (t == 0) logZ_s = m + __logf(s);
    }
    __syncthreads();

    const float logZ = logZ_s;
    const int vid = n >> 8;                      // n / M
    const int cat = inputs[t * V + vid];         // inputs[b, vid], b = t
    buf[(size_t)(1 + n) * B + t] = lg[cat] - logZ;
    if (n == 0) buf[t] = 0.0f;                   // dummy node row 0
}

// ---------------- Kernel B: fused prod+sum layer (float4, 4 nodes/block) ----
__global__ __launch_bounds__(256) void layer_kernel(
    const int* __restrict__ child,   // [E, AR] for this layer (e = i*K + k)
    const float* __restrict__ slog,  // [N, K] for this layer
    float* __restrict__ buf,         // [TOTAL_ROWS, B]
    int out_row0)
{
    __shared__ int ch[4][K * AR];
    __shared__ float lw[4][K];
    const int t = threadIdx.x;
    const int i0 = blockIdx.x * 4;

    if (t < 32) {
        ch[t >> 3][t & 7] = child[(size_t)i0 * (K * AR) + t];
    } else if (t < 36) {
        const int j = t - 32;
        const float* sl = slog + (size_t)(i0 + j) * K;
        const float x0 = sl[0], x1 = sl[1], x2 = sl[2], x3 = sl[3];
        const float m = fmaxf(fmaxf(x0, x1), fmaxf(x2, x3));
        const float lz = m + __logf(__expf(x0 - m) + __expf(x1 - m) +
                                    __expf(x2 - m) + __expf(x3 - m));
        lw[j][0] = x0 - lz; lw[j][1] = x1 - lz; lw[j][2] = x2 - lz; lw[j][3] = x3 - lz;
    }
    __syncthreads();

    const int g = t >> 6;   // node within the 4-node group
    const int l = t & 63;   // float4 column index (4 batch cols per lane)
    const float4* bufv = (const float4*)buf;   // row stride = B/4 = 64 float4

    float4 v[K];
    #pragma unroll
    for (int k = 0; k < K; ++k) {
        const float4 a = bufv[(size_t)ch[g][2 * k]     * (B / 4) + l];
        const float4 b = bufv[(size_t)ch[g][2 * k + 1] * (B / 4) + l];
        const float w = lw[g][k];
        v[k].x = a.x + b.x + w;
        v[k].y = a.y + b.y + w;
        v[k].z = a.z + b.z + w;
        v[k].w = a.w + b.w + w;
    }

    float4 m4;
    m4.x = fmaxf(fmaxf(v[0].x, v[1].x), fmaxf(v[2].x, v[3].x));
    m4.y = fmaxf(fmaxf(v[0].y, v[1].y), fmaxf(v[2].y, v[3].y));
    m4.z = fmaxf(fmaxf(v[0].z, v[1].z), fmaxf(v[2].z, v[3].z));
    m4.w = fmaxf(fmaxf(v[0].w, v[1].w), fmaxf(v[2].w, v[3].w));

    float4 r;
    r.x = m4.x + __logf(__expf(v[0].x - m4.x) + __expf(v[1].x - m4.x) +
                        __expf(v[2].x - m4.x) + __expf(v[3].x - m4.x));
    r.y = m4.y + __logf(__expf(v[0].y - m4.y) + __expf(v[1].y - m4.y) +
                        __expf(v[2].y - m4.y) + __expf(v[3].y - m4.y));
    r.z = m4.z + __logf(__expf(v[0].z - m4.z) + __expf(v[1].z - m4.z) +
                        __expf(v[2].z - m4.z) + __expf(v[3].z - m4.z));
    r.w = m4.w + __logf(__expf(v[0].w - m4.w) + __expf(v[1].w - m4.w) +
                        __expf(v[2].w - m4.w) + __expf(v[3].w - m4.w));

    ((float4*)buf)[(size_t)(out_row0 + i0 + g) * (B / 4) + l] = r;
}

// ---------------- Kernel C: root partials (4 independent accumulators) -----
__global__ __launch_bounds__(256) void root_partial_kernel(
    const float* __restrict__ buf,
    const float* __restrict__ rlog,  // [N]
    float* __restrict__ pm, float* __restrict__ ps)
{
    const int p = blockIdx.x;
    const int t = threadIdx.x;
    const float* last = buf + (size_t)(BASE + (LAYERS - 1) * N) * B;

    float m0 = -INFINITY, s0 = 0.f, m1 = -INFINITY, s1 = 0.f;
    float m2 = -INFINITY, s2 = 0.f, m3 = -INFINITY, s3 = 0.f;

    #define ONL(mm, ss, vv) { const float nm = fmaxf(mm, vv); \
        ss = ss * __expf(mm - nm) + __expf(vv - nm); mm = nm; }

    for (int n = p; n < N; n += 4 * PPART) {
        const float v0 = last[(size_t)(n)             * B + t] + rlog[n];
        const float v1 = last[(size_t)(n + PPART)     * B + t] + rlog[n + PPART];
        const float v2 = last[(size_t)(n + 2 * PPART) * B + t] + rlog[n + 2 * PPART];
        const float v3 = last[(size_t)(n + 3 * PPART) * B + t] + rlog[n + 3 * PPART];
        ONL(m0, s0, v0);
        ONL(m1, s1, v1);
        ONL(m2, s2, v2);
        ONL(m3, s3, v3);
    }
    // merge the 4 accumulators
    ONL(m0, s0, m1 + __logf(s1));
    ONL(m2, s2, m3 + __logf(s3));
    ONL(m0, s0, m2 + __logf(s2));
    #undef ONL

    pm[p * B + t] = m0;
    ps[p * B + t] = s0;
}

// ---------------- Kernel D: combine + root normalizer (two-pass) -----------
__global__ __launch_bounds__(256) void root_combine_kernel(
    const float* __restrict__ rlog,
    const float* __restrict__ pm, const float* __restrict__ ps,
    float* __restrict__ out)
{
    __shared__ float red[256];
    const int t = threadIdx.x;

    // ---- logZ of root logits: independent-accumulator loops ----
    float a0 = -INFINITY, a1 = -INFINITY, a2 = -INFINITY, a3 = -INFINITY;
    #pragma unroll 4
    for (int n = t; n < N; n += 1024) {
        a0 = fmaxf(a0, rlog[n]);
        a1 = fmaxf(a1, rlog[n + 256]);
        a2 = fmaxf(a2, rlog[n + 512]);
        a3 = fmaxf(a3, rlog[n + 768]);
    }
    red[t] = fmaxf(fmaxf(a0, a1), fmaxf(a2, a3));
    __syncthreads();
    for (int off = 128; off >= 1; off >>= 1) {
        if (t < off) red[t] = fmaxf(red[t], red[t + off]);
        __syncthreads();
    }
    const float gm = red[0];
    __syncthreads();

    float b0 = 0.f, b1 = 0.f, b2 = 0.f, b3 = 0.f;
    #pragma unroll 4
    for (int n = t; n < N; n += 1024) {
        b0 += __expf(rlog[n]       - gm);
        b1 += __expf(rlog[n + 256] - gm);
        b2 += __expf(rlog[n + 512] - gm);
        b3 += __expf(rlog[n + 768] - gm);
    }
    red[t] = (b0 + b1) + (b2 + b3);
    __syncthreads();
    for (int off = 128; off >= 1; off >>= 1) {
        if (t < off) red[t] += red[t + off];
        __syncthreads();
    }
    const float logZ = gm + __logf(red[0]);

    // ---- combine partials for batch column t: two-pass, unrolled ----
    float m0 = -INFINITY, m1 = -INFINITY, m2 = -INFINITY, m3 = -INFINITY;
    #pragma unroll 8
    for (int p = 0; p < PPART; p += 4) {
        m0 = fmaxf(m0, pm[(p)     * B + t]);
        m1 = fmaxf(m1, pm[(p + 1) * B + t]);
        m2 = fmaxf(m2, pm[(p + 2) * B + t]);
        m3 = fmaxf(m3, pm[(p + 3) * B + t]);
    }
    const float m = fmaxf(fmaxf(m0, m1), fmaxf(m2, m3));

    float s0 = 0.f, s1 = 0.f, s2 = 0.f, s3 = 0.f;
    #pragma unroll 8
    for (int p = 0; p < PPART; p += 4) {
        s0 += ps[(p)     * B + t] * __expf(pm[(p)     * B + t] - m);
        s1 += ps[(p + 1) * B + t] * __expf(pm[(p + 1) * B + t] - m);
        s2 += ps[(p + 2) * B + t] * __expf(pm[(p + 2) * B + t] - m);
        s3 += ps[(p + 3) * B + t] * __expf(pm[(p + 3) * B + t] - m);
    }
    out[t] = m + __logf((s0 + s1) + (s2 + s3)) - logZ;
}

extern "C" void kernel_launch(void* const* d_in, const int* in_sizes, int n_in,
                              void* d_out, int out_size, void* d_ws, size_t ws_size,
                              hipStream_t stream) {
    const int*   inputs       = (const int*)d_in[0];    // [B, V]
    const float* input_logits = (const float*)d_in[1];  // [NUM_INPUT, CAT]
    const float* sum_logits   = (const float*)d_in[2];  // [LAYERS, N, K]
    const float* root_logits  = (const float*)d_in[3];  // [N]
    const int*   child        = (const int*)d_in[4];    // [LAYERS, E, AR]
    float* out = (float*)d_out;                          // [B, 1]

    float* buf = (float*)d_ws;                           // [TOTAL_ROWS, B]
    const size_t buf_elems = (size_t)TOTAL_ROWS * B;
    float* pm = buf + buf_elems;                         // [PPART, B]
    float* ps = pm + (size_t)PPART * B;                  // [PPART, B]

    input_layer_kernel<<<NUM_INPUT, 256, 0, stream>>>(inputs, input_logits, buf);

    for (int l = 0; l < LAYERS; ++l) {
        layer_kernel<<<N / 4, 256, 0, stream>>>(
            child + (size_t)l * E * AR,
            sum_logits + (size_t)l * N * K,
            buf,
            BASE + l * N);
    }

    root_partial_kernel<<<PPART, 256, 0, stream>>>(buf, root_logits, pm, ps);
    root_combine_kernel<<<1, 256, 0, stream>>>(root_logits, pm, ps, out);
}

// Round 3
// 143.721 us; speedup vs baseline: 2.5620x; 1.6599x over previous
//
#include <hip/hip_runtime.h>
#include <math.h>

#define V 128
#define M 256
#define CAT 64
#define B 256
#define LAYERS 4
#define N 32768
#define K 4
#define AR 2
#define E (N * K)
#define NUM_INPUT (V * M)
#define BASE (1 + NUM_INPUT)
#define TOTAL_ROWS (BASE + LAYERS * N)   // 163841
#define PPART 256

typedef _Float16 half8 __attribute__((ext_vector_type(8)));
typedef _Float16 half4 __attribute__((ext_vector_type(4)));
typedef float float8_t __attribute__((ext_vector_type(8)));

// Per-layer storage offsets: stored = true_value + OFF.  Chosen near the
// negated mean log-marginal magnitude of each tier so fp16 stores small values.
#define OFF_IN 5.2f
__device__ __forceinline__ float layer_off(int l) {
    const float o[4] = {11.4f, 23.5f, 47.5f, 95.5f};
    return o[l];
}
__device__ __forceinline__ float row_off(int row) {
    return (row < BASE) ? OFF_IN : layer_off((row - BASE) >> 15);
}

// ---------------- Kernel A: input layer (4 nodes/block, fp16 out) ----------
__global__ __launch_bounds__(256) void input_layer_kernel(
    const int* __restrict__ inputs,          // [B, V] int32
    const float* __restrict__ input_logits,  // [NUM_INPUT, CAT]
    _Float16* __restrict__ buf)              // [TOTAL_ROWS, B] fp16 (+offsets)
{
    __shared__ float lg[4][CAT];
    __shared__ int cats[B];
    __shared__ float lzs[4];
    const int t = threadIdx.x;
    const int n0 = blockIdx.x * 4;

    lg[t >> 6][t & 63] = input_logits[(size_t)n0 * CAT + t];
    cats[t] = inputs[t * V + (n0 >> 8)];     // vid = n0/M, same for 4 nodes
    __syncthreads();

    const int w = t >> 6;   // wave = node within group
    const int l = t & 63;   // lane
    float x = lg[w][l];
    float m = x;
    #pragma unroll
    for (int off = 32; off >= 1; off >>= 1) m = fmaxf(m, __shfl_xor(m, off));
    float s = __expf(x - m);
    #pragma unroll
    for (int off = 32; off >= 1; off >>= 1) s += __shfl_xor(s, off);
    if (l == 0) lzs[w] = m + __logf(s);
    __syncthreads();

    const float logZ = lzs[w];
    half4 r;
    #pragma unroll
    for (int j = 0; j < 4; ++j) {
        const int c = cats[4 * l + j];
        r[j] = (_Float16)(lg[w][c] - logZ + OFF_IN);
    }
    ((half4*)buf)[(size_t)(1 + n0 + w) * (B / 4) + l] = r;

    if (blockIdx.x == 0 && t < B / 4) {      // dummy row 0: true value 0.0
        half4 z;
        z[0] = z[1] = z[2] = z[3] = (_Float16)OFF_IN;
        ((half4*)buf)[t] = z;
    }
}

// ---------------- Kernel B: fused prod+sum layer (fp16, 8 nodes/block) -----
__global__ __launch_bounds__(256) void layer_kernel(
    const int* __restrict__ child,   // [E, AR] for this layer (e = i*K + k)
    const float* __restrict__ slog,  // [N, K] for this layer
    _Float16* __restrict__ buf,      // [TOTAL_ROWS, B]
    int out_row0, int layer)
{
    __shared__ int ch[8][K * AR];
    __shared__ float w[8][K];
    const int t = threadIdx.x;
    const int i0 = blockIdx.x * 8;

    if (t < 64) ((int*)ch)[t] = child[(size_t)i0 * (K * AR) + t];
    __syncthreads();

    if (t < 32) {
        // coalesced read of 8 nodes x 4 logits; 4-lane-group LSE
        const float x = slog[(size_t)i0 * K + t];
        float mm = fmaxf(x, __shfl_xor(x, 1));
        mm = fmaxf(mm, __shfl_xor(mm, 2));
        float e = __expf(x - mm);
        float ss = e + __shfl_xor(e, 1);
        ss += __shfl_xor(ss, 2);
        const float lz = mm + __logf(ss);
        const int j = t >> 2, k = t & 3;
        w[j][k] = x - lz - row_off(ch[j][2 * k]) - row_off(ch[j][2 * k + 1])
                  + layer_off(layer);
    }
    __syncthreads();

    const int g = t >> 5;   // node within the 8-node group
    const int l = t & 31;   // half8 column index (8 batch cols per lane)
    const half8* bufv = (const half8*)buf;   // row stride = B/8 = 32

    float8_t v[K];
    #pragma unroll
    for (int k = 0; k < K; ++k) {
        const half8 a = bufv[ch[g][2 * k]     * (B / 8) + l];
        const half8 b = bufv[ch[g][2 * k + 1] * (B / 8) + l];
        v[k] = __builtin_convertvector(a, float8_t) +
               __builtin_convertvector(b, float8_t) + w[g][k];
    }

    half8 r;
    #pragma unroll
    for (int j = 0; j < 8; ++j) {
        const float mm = fmaxf(fmaxf(v[0][j], v[1][j]), fmaxf(v[2][j], v[3][j]));
        const float ss = __expf(v[0][j] - mm) + __expf(v[1][j] - mm) +
                         __expf(v[2][j] - mm) + __expf(v[3][j] - mm);
        r[j] = (_Float16)(mm + __logf(ss));
    }
    ((half8*)buf)[(out_row0 + i0 + g) * (B / 8) + l] = r;
}

// ---------------- Kernel C: root partials (4 independent accumulators) -----
__global__ __launch_bounds__(256) void root_partial_kernel(
    const _Float16* __restrict__ buf,
    const float* __restrict__ rlog,  // [N]
    float* __restrict__ pm, float* __restrict__ ps)
{
    const int p = blockIdx.x;
    const int t = threadIdx.x;
    const _Float16* last = buf + (size_t)(BASE + (LAYERS - 1) * N) * B;
    const float off3 = layer_off(LAYERS - 1);

    float m0 = -INFINITY, s0 = 0.f, m1 = -INFINITY, s1 = 0.f;
    float m2 = -INFINITY, s2 = 0.f, m3 = -INFINITY, s3 = 0.f;

    #define ONL(mm, ss, vv) { const float nm = fmaxf(mm, vv); \
        ss = ss * __expf(mm - nm) + __expf(vv - nm); mm = nm; }

    for (int n = p; n < N; n += 4 * PPART) {
        const float v0 = (float)last[(size_t)(n)             * B + t] + (rlog[n]             - off3);
        const float v1 = (float)last[(size_t)(n + PPART)     * B + t] + (rlog[n + PPART]     - off3);
        const float v2 = (float)last[(size_t)(n + 2 * PPART) * B + t] + (rlog[n + 2 * PPART] - off3);
        const float v3 = (float)last[(size_t)(n + 3 * PPART) * B + t] + (rlog[n + 3 * PPART] - off3);
        ONL(m0, s0, v0);
        ONL(m1, s1, v1);
        ONL(m2, s2, v2);
        ONL(m3, s3, v3);
    }
    ONL(m0, s0, m1 + __logf(s1));
    ONL(m2, s2, m3 + __logf(s3));
    ONL(m0, s0, m2 + __logf(s2));
    #undef ONL

    pm[p * B + t] = m0;
    ps[p * B + t] = s0;
}

// ---------------- Kernel D: combine + root normalizer (two-pass) -----------
__global__ __launch_bounds__(256) void root_combine_kernel(
    const float* __restrict__ rlog,
    const float* __restrict__ pm, const float* __restrict__ ps,
    float* __restrict__ out)
{
    __shared__ float red[256];
    const int t = threadIdx.x;

    float a0 = -INFINITY, a1 = -INFINITY, a2 = -INFINITY, a3 = -INFINITY;
    #pragma unroll 4
    for (int n = t; n < N; n += 1024) {
        a0 = fmaxf(a0, rlog[n]);
        a1 = fmaxf(a1, rlog[n + 256]);
        a2 = fmaxf(a2, rlog[n + 512]);
        a3 = fmaxf(a3, rlog[n + 768]);
    }
    red[t] = fmaxf(fmaxf(a0, a1), fmaxf(a2, a3));
    __syncthreads();
    for (int off = 128; off >= 1; off >>= 1) {
        if (t < off) red[t] = fmaxf(red[t], red[t + off]);
        __syncthreads();
    }
    const float gm = red[0];
    __syncthreads();

    float b0 = 0.f, b1 = 0.f, b2 = 0.f, b3 = 0.f;
    #pragma unroll 4
    for (int n = t; n < N; n += 1024) {
        b0 += __expf(rlog[n]       - gm);
        b1 += __expf(rlog[n + 256] - gm);
        b2 += __expf(rlog[n + 512] - gm);
        b3 += __expf(rlog[n + 768] - gm);
    }
    red[t] = (b0 + b1) + (b2 + b3);
    __syncthreads();
    for (int off = 128; off >= 1; off >>= 1) {
        if (t < off) red[t] += red[t + off];
        __syncthreads();
    }
    const float logZ = gm + __logf(red[0]);

    float m0 = -INFINITY, m1 = -INFINITY, m2 = -INFINITY, m3 = -INFINITY;
    #pragma unroll 8
    for (int p = 0; p < PPART; p += 4) {
        m0 = fmaxf(m0, pm[(p)     * B + t]);
        m1 = fmaxf(m1, pm[(p + 1) * B + t]);
        m2 = fmaxf(m2, pm[(p + 2) * B + t]);
        m3 = fmaxf(m3, pm[(p + 3) * B + t]);
    }
    const float m = fmaxf(fmaxf(m0, m1), fmaxf(m2, m3));

    float s0 = 0.f, s1 = 0.f, s2 = 0.f, s3 = 0.f;
    #pragma unroll 8
    for (int p = 0; p < PPART; p += 4) {
        s0 += ps[(p)     * B + t] * __expf(pm[(p)     * B + t] - m);
        s1 += ps[(p + 1) * B + t] * __expf(pm[(p + 1) * B + t] - m);
        s2 += ps[(p + 2) * B + t] * __expf(pm[(p + 2) * B + t] - m);
        s3 += ps[(p + 3) * B + t] * __expf(pm[(p + 3) * B + t] - m);
    }
    out[t] = m + __logf((s0 + s1) + (s2 + s3)) - logZ;
}

extern "C" void kernel_launch(void* const* d_in, const int* in_sizes, int n_in,
                              void* d_out, int out_size, void* d_ws, size_t ws_size,
                              hipStream_t stream) {
    const int*   inputs       = (const int*)d_in[0];    // [B, V]
    const float* input_logits = (const float*)d_in[1];  // [NUM_INPUT, CAT]
    const float* sum_logits   = (const float*)d_in[2];  // [LAYERS, N, K]
    const float* root_logits  = (const float*)d_in[3];  // [N]
    const int*   child        = (const int*)d_in[4];    // [LAYERS, E, AR]
    float* out = (float*)d_out;                          // [B, 1]

    _Float16* buf = (_Float16*)d_ws;                     // [TOTAL_ROWS, B] fp16
    float* pm = (float*)(buf + (size_t)TOTAL_ROWS * B);  // [PPART, B]
    float* ps = pm + (size_t)PPART * B;                  // [PPART, B]

    input_layer_kernel<<<NUM_INPUT / 4, 256, 0, stream>>>(inputs, input_logits, buf);

    for (int l = 0; l < LAYERS; ++l) {
        layer_kernel<<<N / 8, 256, 0, stream>>>(
            child + (size_t)l * E * AR,
            sum_logits + (size_t)l * N * K,
            buf,
            BASE + l * N, l);
    }

    root_partial_kernel<<<PPART, 256, 0, stream>>>(buf, root_logits, pm, ps);
    root_combine_kernel<<<1, 256, 0, stream>>>(root_logits, pm, ps, out);
}

// Round 4
// 127.938 us; speedup vs baseline: 2.8781x; 1.1234x over previous
//
#include <hip/hip_runtime.h>
#include <math.h>

#define V 128
#define M 256
#define CAT 64
#define B 256
#define LAYERS 4
#define N 32768
#define K 4
#define AR 2
#define E (N * K)
#define NUM_INPUT (V * M)
#define BASE (1 + NUM_INPUT)
#define TOTAL_ROWS (BASE + LAYERS * N)   // 163841
#define L3N 32                 // nodes per block in fused layer-3 kernel
#define NPART (N / L3N)        // 1024 first-stage partials
#define R1BLK 32               // second-stage partial count

typedef _Float16 half8 __attribute__((ext_vector_type(8)));
typedef _Float16 half4 __attribute__((ext_vector_type(4)));
typedef float float8_t __attribute__((ext_vector_type(8)));

// Per-layer storage offsets: stored = true_value + OFF (keeps fp16 small).
#define OFF_IN 5.2f
__device__ __forceinline__ float layer_off(int l) {
    const float o[4] = {11.4f, 23.5f, 47.5f, 95.5f};
    return o[l];
}
__device__ __forceinline__ float row_off(int row) {
    return (row < BASE) ? OFF_IN : layer_off((row - BASE) >> 15);
}

// ---------------- Kernel A: input layer (4 nodes/block, fp16 out) ----------
__global__ __launch_bounds__(256) void input_layer_kernel(
    const int* __restrict__ inputs,          // [B, V] int32
    const float* __restrict__ input_logits,  // [NUM_INPUT, CAT]
    _Float16* __restrict__ buf)              // [TOTAL_ROWS, B] fp16 (+offsets)
{
    __shared__ float lg[4][CAT];
    __shared__ int cats[B];
    __shared__ float lzs[4];
    const int t = threadIdx.x;
    const int n0 = blockIdx.x * 4;

    lg[t >> 6][t & 63] = input_logits[(size_t)n0 * CAT + t];
    cats[t] = inputs[t * V + (n0 >> 8)];     // vid = n0/M, same for 4 nodes
    __syncthreads();

    const int w = t >> 6;   // wave = node within group
    const int l = t & 63;   // lane
    float x = lg[w][l];
    float m = x;
    #pragma unroll
    for (int off = 32; off >= 1; off >>= 1) m = fmaxf(m, __shfl_xor(m, off));
    float s = __expf(x - m);
    #pragma unroll
    for (int off = 32; off >= 1; off >>= 1) s += __shfl_xor(s, off);
    if (l == 0) lzs[w] = m + __logf(s);
    __syncthreads();

    const float logZ = lzs[w];
    half4 r;
    #pragma unroll
    for (int j = 0; j < 4; ++j) {
        const int c = cats[4 * l + j];
        r[j] = (_Float16)(lg[w][c] - logZ + OFF_IN);
    }
    ((half4*)buf)[(size_t)(1 + n0 + w) * (B / 4) + l] = r;

    if (blockIdx.x == 0 && t < B / 4) {      // dummy row 0: true value 0.0
        half4 z;
        z[0] = z[1] = z[2] = z[3] = (_Float16)OFF_IN;
        ((half4*)buf)[t] = z;
    }
}

// ---------------- Kernel B: fused prod+sum layer (fp16, 8 nodes/block) -----
__global__ __launch_bounds__(256) void layer_kernel(
    const int* __restrict__ child,   // [E, AR] for this layer (e = i*K + k)
    const float* __restrict__ slog,  // [N, K] for this layer
    _Float16* __restrict__ buf,      // [TOTAL_ROWS, B]
    int out_row0, int layer)
{
    __shared__ int ch[8][K * AR];
    __shared__ float w[8][K];
    const int t = threadIdx.x;
    const int i0 = blockIdx.x * 8;

    if (t < 64) ((int*)ch)[t] = child[(size_t)i0 * (K * AR) + t];
    __syncthreads();

    if (t < 32) {
        const float x = slog[(size_t)i0 * K + t];
        float mm = fmaxf(x, __shfl_xor(x, 1));
        mm = fmaxf(mm, __shfl_xor(mm, 2));
        float e = __expf(x - mm);
        float ss = e + __shfl_xor(e, 1);
        ss += __shfl_xor(ss, 2);
        const float lz = mm + __logf(ss);
        const int j = t >> 2, k = t & 3;
        w[j][k] = x - lz - row_off(ch[j][2 * k]) - row_off(ch[j][2 * k + 1])
                  + layer_off(layer);
    }
    __syncthreads();

    const int g = t >> 5;   // node within the 8-node group
    const int l = t & 31;   // half8 column index
    const half8* bufv = (const half8*)buf;   // row stride = B/8 = 32

    float8_t v[K];
    #pragma unroll
    for (int k = 0; k < K; ++k) {
        const half8 a = bufv[ch[g][2 * k]     * (B / 8) + l];
        const half8 b = bufv[ch[g][2 * k + 1] * (B / 8) + l];
        v[k] = __builtin_convertvector(a, float8_t) +
               __builtin_convertvector(b, float8_t) + w[g][k];
    }

    half8 r;
    #pragma unroll
    for (int j = 0; j < 8; ++j) {
        const float mm = fmaxf(fmaxf(v[0][j], v[1][j]), fmaxf(v[2][j], v[3][j]));
        const float ss = __expf(v[0][j] - mm) + __expf(v[1][j] - mm) +
                         __expf(v[2][j] - mm) + __expf(v[3][j] - mm);
        r[j] = (_Float16)(mm + __logf(ss));
    }
    ((half8*)buf)[(out_row0 + i0 + g) * (B / 8) + l] = r;
}

// ---------------- Kernel B3: fused layer-3 + root partial ------------------
// Computes layer-3 node values in f32 (never stored), adds root edge logits,
// and reduces the block's 32 nodes into one (m, s) partial per batch column.
__global__ __launch_bounds__(1024) void layer3_root_kernel(
    const int* __restrict__ child,   // layer-3 [E, AR]
    const float* __restrict__ slog,  // layer-3 [N, K]
    const _Float16* __restrict__ buf,
    const float* __restrict__ rlog,  // [N]
    float* __restrict__ pm, float* __restrict__ ps)  // [NPART, B]
{
    __shared__ int ch[L3N][K * AR];
    __shared__ float w[L3N][K];
    __shared__ float rl[L3N];
    __shared__ float vmat[B][L3N + 1];   // [col][node-in-block], padded
    const int t = threadIdx.x;
    const int i0 = blockIdx.x * L3N;
    const float off3 = layer_off(3);

    if (t < L3N * 8) ((int*)ch)[t] = child[(size_t)i0 * (K * AR) + t];
    if (t >= 512 && t < 512 + L3N) rl[t - 512] = rlog[i0 + (t - 512)];
    __syncthreads();

    if (t < L3N * 4) {   // 128 threads; 4-lane-group LSE of sum logits
        const float x = slog[(size_t)i0 * K + t];
        float mm = fmaxf(x, __shfl_xor(x, 1));
        mm = fmaxf(mm, __shfl_xor(mm, 2));
        float e = __expf(x - mm);
        float ss = e + __shfl_xor(e, 1);
        ss += __shfl_xor(ss, 2);
        const float lz = mm + __logf(ss);
        const int j = t >> 2, k = t & 3;
        w[j][k] = x - lz - row_off(ch[j][2 * k]) - row_off(ch[j][2 * k + 1])
                  + off3;
    }
    __syncthreads();

    const int g = t >> 5;   // node within block (0..31)
    const int l = t & 31;   // half8 column index

    const half8* bufv = (const half8*)buf;
    float8_t v[K];
    #pragma unroll
    for (int k = 0; k < K; ++k) {
        const half8 a = bufv[ch[g][2 * k]     * (B / 8) + l];
        const half8 b = bufv[ch[g][2 * k + 1] * (B / 8) + l];
        v[k] = __builtin_convertvector(a, float8_t) +
               __builtin_convertvector(b, float8_t) + w[g][k];
    }

    const float radd = rl[g] - off3;   // de-offset + root edge logit
    #pragma unroll
    for (int j = 0; j < 8; ++j) {
        const float mm = fmaxf(fmaxf(v[0][j], v[1][j]), fmaxf(v[2][j], v[3][j]));
        const float ss = __expf(v[0][j] - mm) + __expf(v[1][j] - mm) +
                         __expf(v[2][j] - mm) + __expf(v[3][j] - mm);
        vmat[8 * l + j][g] = mm + __logf(ss) + radd;
    }
    __syncthreads();

    if (t < B) {   // per-column LSE over the block's 32 nodes
        float m = -INFINITY;
        #pragma unroll
        for (int q = 0; q < L3N; ++q) m = fmaxf(m, vmat[t][q]);
        float s = 0.0f;
        #pragma unroll
        for (int q = 0; q < L3N; ++q) s += __expf(vmat[t][q] - m);
        pm[blockIdx.x * B + t] = m;
        ps[blockIdx.x * B + t] = s;
    }
}

// ---------------- Kernel C: partial tree reduce 1024 -> 32 -----------------
__global__ __launch_bounds__(256) void root_reduce1(
    const float* __restrict__ pm, const float* __restrict__ ps,
    float* __restrict__ pm2, float* __restrict__ ps2)
{
    const int j = blockIdx.x;        // 0..R1BLK-1
    const int c = threadIdx.x;
    const int Q = NPART / R1BLK;     // 32
    const int p0 = j * Q;

    float m = -INFINITY;
    #pragma unroll 8
    for (int q = 0; q < Q; ++q) m = fmaxf(m, pm[(p0 + q) * B + c]);
    float s = 0.0f;
    #pragma unroll 8
    for (int q = 0; q < Q; ++q)
        s += ps[(p0 + q) * B + c] * __expf(pm[(p0 + q) * B + c] - m);
    pm2[j * B + c] = m;
    ps2[j * B + c] = s;
}

// ---------------- Kernel D: combine + root normalizer ----------------------
__global__ __launch_bounds__(256) void root_combine_kernel(
    const float* __restrict__ rlog,
    const float* __restrict__ pm2, const float* __restrict__ ps2,
    float* __restrict__ out)
{
    __shared__ float red[256];
    const int t = threadIdx.x;

    // logZ of root logits
    float a0 = -INFINITY, a1 = -INFINITY, a2 = -INFINITY, a3 = -INFINITY;
    #pragma unroll 4
    for (int n = t; n < N; n += 1024) {
        a0 = fmaxf(a0, rlog[n]);
        a1 = fmaxf(a1, rlog[n + 256]);
        a2 = fmaxf(a2, rlog[n + 512]);
        a3 = fmaxf(a3, rlog[n + 768]);
    }
    red[t] = fmaxf(fmaxf(a0, a1), fmaxf(a2, a3));
    __syncthreads();
    for (int off = 128; off >= 1; off >>= 1) {
        if (t < off) red[t] = fmaxf(red[t], red[t + off]);
        __syncthreads();
    }
    const float gm = red[0];
    __syncthreads();

    float b0 = 0.f, b1 = 0.f, b2 = 0.f, b3 = 0.f;
    #pragma unroll 4
    for (int n = t; n < N; n += 1024) {
        b0 += __expf(rlog[n]       - gm);
        b1 += __expf(rlog[n + 256] - gm);
        b2 += __expf(rlog[n + 512] - gm);
        b3 += __expf(rlog[n + 768] - gm);
    }
    red[t] = (b0 + b1) + (b2 + b3);
    __syncthreads();
    for (int off = 128; off >= 1; off >>= 1) {
        if (t < off) red[t] += red[t + off];
        __syncthreads();
    }
    const float logZ = gm + __logf(red[0]);

    // combine R1BLK partials for batch column t
    float m = -INFINITY;
    #pragma unroll 8
    for (int p = 0; p < R1BLK; ++p) m = fmaxf(m, pm2[p * B + t]);
    float s = 0.0f;
    #pragma unroll 8
    for (int p = 0; p < R1BLK; ++p)
        s += ps2[p * B + t] * __expf(pm2[p * B + t] - m);
    out[t] = m + __logf(s) - logZ;
}

extern "C" void kernel_launch(void* const* d_in, const int* in_sizes, int n_in,
                              void* d_out, int out_size, void* d_ws, size_t ws_size,
                              hipStream_t stream) {
    const int*   inputs       = (const int*)d_in[0];    // [B, V]
    const float* input_logits = (const float*)d_in[1];  // [NUM_INPUT, CAT]
    const float* sum_logits   = (const float*)d_in[2];  // [LAYERS, N, K]
    const float* root_logits  = (const float*)d_in[3];  // [N]
    const int*   child        = (const int*)d_in[4];    // [LAYERS, E, AR]
    float* out = (float*)d_out;                          // [B, 1]

    _Float16* buf = (_Float16*)d_ws;                     // [TOTAL_ROWS, B] fp16
    float* pm  = (float*)(buf + (size_t)TOTAL_ROWS * B); // [NPART, B]
    float* ps  = pm  + (size_t)NPART * B;                // [NPART, B]
    float* pm2 = ps  + (size_t)NPART * B;                // [R1BLK, B]
    float* ps2 = pm2 + (size_t)R1BLK * B;                // [R1BLK, B]

    input_layer_kernel<<<NUM_INPUT / 4, 256, 0, stream>>>(inputs, input_logits, buf);

    for (int l = 0; l < LAYERS - 1; ++l) {
        layer_kernel<<<N / 8, 256, 0, stream>>>(
            child + (size_t)l * E * AR,
            sum_logits + (size_t)l * N * K,
            buf,
            BASE + l * N, l);
    }

    layer3_root_kernel<<<NPART, 1024, 0, stream>>>(
        child + (size_t)(LAYERS - 1) * E * AR,
        sum_logits + (size_t)(LAYERS - 1) * N * K,
        buf, root_logits, pm, ps);

    root_reduce1<<<R1BLK, 256, 0, stream>>>(pm, ps, pm2, ps2);
    root_combine_kernel<<<1, 256, 0, stream>>>(root_logits, pm2, ps2, out);
}